// Round 1
// baseline (557.759 us; speedup 1.0000x reference)
//
#include <hip/hip_runtime.h>
#include <math.h>

#define NN 50000
#define NE 800000

// ---------------- CSR build ----------------

__global__ void k_hist(const int* __restrict__ dst, int* __restrict__ deg) {
    int e = blockIdx.x * blockDim.x + threadIdx.x;
    if (e < NE) atomicAdd(&deg[dst[e]], 1);
}

__global__ void k_scan_part(const int* __restrict__ deg, int* __restrict__ partials) {
    __shared__ int s[1024];
    int idx = blockIdx.x * 1024 + threadIdx.x;
    s[threadIdx.x] = (idx < NN) ? deg[idx] : 0;
    for (int off = 512; off > 0; off >>= 1) {
        __syncthreads();
        if (threadIdx.x < off) s[threadIdx.x] += s[threadIdx.x + off];
    }
    if (threadIdx.x == 0) partials[blockIdx.x] = s[0];
}

__global__ void k_scan_top(int* __restrict__ partials, int* __restrict__ row_start, int n) {
    if (threadIdx.x == 0 && blockIdx.x == 0) {
        int acc = 0;
        for (int i = 0; i < n; ++i) { int v = partials[i]; partials[i] = acc; acc += v; }
        row_start[NN] = acc;
    }
}

__global__ void k_scan_final(const int* __restrict__ deg, const int* __restrict__ partials,
                             int* __restrict__ row_start) {
    __shared__ int s[1024];
    int idx = blockIdx.x * 1024 + threadIdx.x;
    int v = (idx < NN) ? deg[idx] : 0;
    s[threadIdx.x] = v;
    for (int off = 1; off < 1024; off <<= 1) {
        __syncthreads();
        int tmp = (threadIdx.x >= off) ? s[threadIdx.x - off] : 0;
        __syncthreads();
        s[threadIdx.x] += tmp;
    }
    if (idx < NN) row_start[idx] = partials[blockIdx.x] + s[threadIdx.x] - v;
}

__global__ void k_scatter(const int* __restrict__ src, const int* __restrict__ dst,
                          const int* __restrict__ row_start, int* __restrict__ cursor,
                          int* __restrict__ col_idx) {
    int e = blockIdx.x * blockDim.x + threadIdx.x;
    if (e < NE) {
        int d = dst[e];
        int slot = atomicAdd(&cursor[d], 1);
        col_idx[row_start[d] + slot] = src[e];
    }
}

// ---------------- mean aggregation (wave per node) ----------------

__global__ __launch_bounds__(256)
void k_agg(const float* __restrict__ feat, const int* __restrict__ row_start,
           const int* __restrict__ col_idx, float* __restrict__ outp) {
    int node = (blockIdx.x * 256 + threadIdx.x) >> 6;
    int lane = threadIdx.x & 63;
    if (node >= NN) return;
    int beg = row_start[node], end = row_start[node + 1];
    float sx = 0.f, sy = 0.f;
    for (int j = beg; j < end; ++j) {
        int s = col_idx[j];
        float2 v = *(const float2*)&feat[(size_t)s * 128 + lane * 2];
        sx += v.x; sy += v.y;
    }
    float inv = 1.0f / fmaxf((float)(end - beg), 1.0f);
    float2 o; o.x = sx * inv; o.y = sy * inv;
    *(float2*)&outp[(size_t)node * 128 + lane * 2] = o;
}

// ---------------- f32 GEMM: out = f(A@W [+ A2@W2] + b [+ addsrc]) ----------------
// tile: 64 rows x 128 cols per block, 256 threads, thread = 8 rows x 4 cols.

template<int DUAL, int DOELU, int DOADD>
__global__ __launch_bounds__(256)
void k_gemm(const float* __restrict__ A, const float* __restrict__ A2,
            const float* __restrict__ W, const float* __restrict__ W2,
            const float* __restrict__ bias, const float* __restrict__ addsrc,
            float* __restrict__ out) {
    __shared__ float sW[64][128];   // 32 KB
    __shared__ float sAt[64][68];   // 17.4 KB, transposed [k][r], padded
    const int t = threadIdx.x;
    const int row0 = blockIdx.x * 64;
    const int tc = (t & 31) * 4;    // col base
    const int tr = (t >> 5) * 8;    // row base within tile

    float acc[8][4];
#pragma unroll
    for (int i = 0; i < 8; ++i)
#pragma unroll
        for (int j = 0; j < 4; ++j) acc[i][j] = 0.f;

    const int npass = DUAL ? 2 : 1;
    for (int m = 0; m < npass; ++m) {
        const float* Ac = m ? A2 : A;
        const float* Wc = m ? W2 : W;
        for (int kc = 0; kc < 128; kc += 64) {
            __syncthreads();
            // stage W chunk [64][128]
#pragma unroll
            for (int i = 0; i < 8; ++i) {
                int idx = t + i * 256;
                int kk = idx >> 5;
                int cc = (idx & 31) * 4;
                *(float4*)&sW[kk][cc] = *(const float4*)&Wc[(kc + kk) * 128 + cc];
            }
            // stage A chunk transposed [k][r]
#pragma unroll
            for (int i = 0; i < 4; ++i) {
                int idx = t + i * 256;
                int r = idx >> 4;
                int kk = (idx & 15) * 4;
                float4 v = make_float4(0.f, 0.f, 0.f, 0.f);
                if (row0 + r < NN) v = *(const float4*)&Ac[(size_t)(row0 + r) * 128 + kc + kk];
                sAt[kk + 0][r] = v.x; sAt[kk + 1][r] = v.y;
                sAt[kk + 2][r] = v.z; sAt[kk + 3][r] = v.w;
            }
            __syncthreads();
#pragma unroll
            for (int k = 0; k < 64; ++k) {
                float4 a0 = *(float4*)&sAt[k][tr];
                float4 a1 = *(float4*)&sAt[k][tr + 4];
                float4 w  = *(float4*)&sW[k][tc];
                float av[8] = {a0.x, a0.y, a0.z, a0.w, a1.x, a1.y, a1.z, a1.w};
                float wv[4] = {w.x, w.y, w.z, w.w};
#pragma unroll
                for (int i = 0; i < 8; ++i)
#pragma unroll
                    for (int j = 0; j < 4; ++j)
                        acc[i][j] = fmaf(av[i], wv[j], acc[i][j]);
            }
        }
    }

    float4 bv = *(const float4*)&bias[tc];
    float bb[4] = {bv.x, bv.y, bv.z, bv.w};
#pragma unroll
    for (int i = 0; i < 8; ++i) {
        int r = row0 + tr + i;
        if (r < NN) {
            float o[4];
#pragma unroll
            for (int j = 0; j < 4; ++j) {
                float v = acc[i][j] + bb[j];
                if (DOELU) v = (v > 0.f) ? v : expm1f(v);
                o[j] = v;
            }
            if (DOADD) {
                float4 ad = *(const float4*)&addsrc[(size_t)r * 128 + tc];
                o[0] += ad.x; o[1] += ad.y; o[2] += ad.z; o[3] += ad.w;
            }
            *(float4*)&out[(size_t)r * 128 + tc] = make_float4(o[0], o[1], o[2], o[3]);
        }
    }
}

// ---------------- launch ----------------

extern "C" void kernel_launch(void* const* d_in, const int* in_sizes, int n_in,
                              void* d_out, int out_size, void* d_ws, size_t ws_size,
                              hipStream_t stream) {
    const float* h        = (const float*)d_in[0];
    const int*   src      = (const int*)d_in[1];
    const int*   dst      = (const int*)d_in[2];
    const float* W_skip1  = (const float*)d_in[3];
    const float* b_skip1  = (const float*)d_in[4];
    const float* W_skip2  = (const float*)d_in[5];
    const float* b_skip2  = (const float*)d_in[6];
    const float* W_self1  = (const float*)d_in[7];
    const float* W_neigh1 = (const float*)d_in[8];
    const float* b_conv1  = (const float*)d_in[9];
    const float* W_si1    = (const float*)d_in[10];
    const float* b_si1    = (const float*)d_in[11];
    const float* W_si2    = (const float*)d_in[12];
    const float* b_si2    = (const float*)d_in[13];
    const float* W_self2  = (const float*)d_in[14];
    const float* W_neigh2 = (const float*)d_in[15];
    const float* b_conv2  = (const float*)d_in[16];
    float* out = (float*)d_out;

    char* ws = (char*)d_ws;
    int* deg       = (int*)ws;            // [50048]
    int* cursor    = deg + 50048;         // [50048]
    int* row_start = deg + 100096;        // [50001] padded to 150208
    int* partials  = deg + 150208;        // [64]
    int* col_idx   = deg + 150272;        // [800000]
    float* F0 = (float*)(ws + 3801088);   // [6400000]
    float* F1 = F0 + 6400000;             // [6400000]

    // zero deg + cursor
    hipMemsetAsync(ws, 0, 100096 * sizeof(int), stream);

    k_hist<<<(NE + 255) / 256, 256, 0, stream>>>(dst, deg);
    k_scan_part<<<49, 1024, 0, stream>>>(deg, partials);
    k_scan_top<<<1, 64, 0, stream>>>(partials, row_start, 49);
    k_scan_final<<<49, 1024, 0, stream>>>(deg, partials, row_start);
    k_scatter<<<(NE + 255) / 256, 256, 0, stream>>>(src, dst, row_start, cursor, col_idx);

    const int GB = (NN + 63) / 64;  // 782 blocks

    // h_skip path: F0 = ELU(h@W_skip1+b) ; out = F0@W_skip2+b
    k_gemm<0, 1, 0><<<GB, 256, 0, stream>>>(h, nullptr, W_skip1, nullptr, b_skip1, nullptr, F0);
    k_gemm<0, 0, 0><<<GB, 256, 0, stream>>>(F0, nullptr, W_skip2, nullptr, b_skip2, nullptr, out);

    // SAGE layer 1: F0 = mean-agg(h); F1 = ELU(h@W_self1 + F0@W_neigh1 + b)
    k_agg<<<(NN * 64 + 255) / 256, 256, 0, stream>>>(h, row_start, col_idx, F0);
    k_gemm<1, 1, 0><<<GB, 256, 0, stream>>>(h, F0, W_self1, W_neigh1, b_conv1, nullptr, F1);

    // self-interaction MLP: F0 = ELU(F1@W_si1+b); F1 = ELU(F0@W_si2+b)
    k_gemm<0, 1, 0><<<GB, 256, 0, stream>>>(F1, nullptr, W_si1, nullptr, b_si1, nullptr, F0);
    k_gemm<0, 1, 0><<<GB, 256, 0, stream>>>(F0, nullptr, W_si2, nullptr, b_si2, nullptr, F1);

    // SAGE layer 2 + residual: F0 = mean-agg(F1); out = F1@W_self2 + F0@W_neigh2 + b + out
    k_agg<<<(NN * 64 + 255) / 256, 256, 0, stream>>>(F1, row_start, col_idx, F0);
    k_gemm<1, 0, 1><<<GB, 256, 0, stream>>>(F1, F0, W_self2, W_neigh2, b_conv2, out, out);
}

// Round 2
// 388.637 us; speedup vs baseline: 1.4352x; 1.4352x over previous
//
#include <hip/hip_runtime.h>
#include <math.h>

#define NN 50000
#define NE 800000

typedef __attribute__((ext_vector_type(8))) short short8;
typedef __attribute__((ext_vector_type(4))) float floatx4;

__device__ __forceinline__ unsigned short f2bf(float f) {
    unsigned u = __float_as_uint(f);
    unsigned r = (u + 0x7fff + ((u >> 16) & 1)) >> 16;
    return (unsigned short)r;
}
__device__ __forceinline__ float bf2f(unsigned short h) {
    return __uint_as_float(((unsigned)h) << 16);
}

// ---------------- CSR build ----------------

__global__ void k_hist(const int* __restrict__ dst, int* __restrict__ deg) {
    int e = blockIdx.x * blockDim.x + threadIdx.x;
    if (e < NE) atomicAdd(&deg[dst[e]], 1);
}

__global__ void k_scan_part(const int* __restrict__ deg, int* __restrict__ partials) {
    __shared__ int s[1024];
    int idx = blockIdx.x * 1024 + threadIdx.x;
    s[threadIdx.x] = (idx < NN) ? deg[idx] : 0;
    for (int off = 512; off > 0; off >>= 1) {
        __syncthreads();
        if (threadIdx.x < off) s[threadIdx.x] += s[threadIdx.x + off];
    }
    if (threadIdx.x == 0) partials[blockIdx.x] = s[0];
}

__global__ void k_scan_top(int* __restrict__ partials, int* __restrict__ row_start, int n) {
    if (threadIdx.x == 0 && blockIdx.x == 0) {
        int acc = 0;
        for (int i = 0; i < n; ++i) { int v = partials[i]; partials[i] = acc; acc += v; }
        row_start[NN] = acc;
    }
}

__global__ void k_scan_final(const int* __restrict__ deg, const int* __restrict__ partials,
                             int* __restrict__ row_start) {
    __shared__ int s[1024];
    int idx = blockIdx.x * 1024 + threadIdx.x;
    int v = (idx < NN) ? deg[idx] : 0;
    s[threadIdx.x] = v;
    for (int off = 1; off < 1024; off <<= 1) {
        __syncthreads();
        int tmp = (threadIdx.x >= off) ? s[threadIdx.x - off] : 0;
        __syncthreads();
        s[threadIdx.x] += tmp;
    }
    if (idx < NN) row_start[idx] = partials[blockIdx.x] + s[threadIdx.x] - v;
}

__global__ void k_scatter(const int* __restrict__ src, const int* __restrict__ dst,
                          const int* __restrict__ row_start, int* __restrict__ cursor,
                          int* __restrict__ col_idx) {
    int e = blockIdx.x * blockDim.x + threadIdx.x;
    if (e < NE) {
        int d = dst[e];
        int slot = atomicAdd(&cursor[d], 1);
        col_idx[row_start[d] + slot] = src[e];
    }
}

// ---------------- f32 -> bf16 convert ----------------

__global__ __launch_bounds__(256)
void k_cvt(const float* __restrict__ src, unsigned short* __restrict__ dst) {
    int i = (blockIdx.x * 256 + threadIdx.x) * 8;
    float4 a = *(const float4*)&src[i];
    float4 b = *(const float4*)&src[i + 4];
    short8 v;
    v[0] = (short)f2bf(a.x); v[1] = (short)f2bf(a.y);
    v[2] = (short)f2bf(a.z); v[3] = (short)f2bf(a.w);
    v[4] = (short)f2bf(b.x); v[5] = (short)f2bf(b.y);
    v[6] = (short)f2bf(b.z); v[7] = (short)f2bf(b.w);
    *(short8*)&dst[i] = v;
}

// ---------------- pack W (f32 [128][128]) into MFMA-B bf16 layout ----------------
// chunk q = (cb*4 + ks)*64 + lane, lane = n + 16*g: holds W[ks*32+g*8+j][cb*16+n], j=0..7

__global__ __launch_bounds__(256)
void k_packW(const float* w0, const float* w1, const float* w2, const float* w3,
             const float* w4, const float* w5, const float* w6, const float* w7,
             short* __restrict__ wpk) {
    const float* W;
    switch (blockIdx.x) {
        case 0: W = w0; break; case 1: W = w1; break;
        case 2: W = w2; break; case 3: W = w3; break;
        case 4: W = w4; break; case 5: W = w5; break;
        case 6: W = w6; break; default: W = w7; break;
    }
    short* dst = wpk + (size_t)blockIdx.x * 16384;
#pragma unroll
    for (int i = 0; i < 8; ++i) {
        int q = threadIdx.x + i * 256;
        int cb = q >> 8, ks = (q >> 6) & 3, lane = q & 63;
        int n = lane & 15, g = lane >> 4;
        int col = cb * 16 + n, krow = ks * 32 + g * 8;
        short8 v;
#pragma unroll
        for (int j = 0; j < 8; ++j)
            v[j] = (short)f2bf(W[(krow + j) * 128 + col]);
        *(short8*)&dst[q * 8] = v;
    }
}

// ---------------- mean aggregation (wave per node, bf16 feats) ----------------

__global__ __launch_bounds__(256)
void k_agg(const unsigned short* __restrict__ feat, const int* __restrict__ row_start,
           const int* __restrict__ col_idx, unsigned short* __restrict__ outp) {
    int node = (blockIdx.x * 256 + threadIdx.x) >> 6;
    int lane = threadIdx.x & 63;
    if (node >= NN) return;
    int beg = row_start[node], end = row_start[node + 1];
    float sx = 0.f, sy = 0.f;
    for (int j = beg; j < end; ++j) {
        int s = col_idx[j];
        unsigned v = *(const unsigned*)&feat[(size_t)s * 128 + lane * 2];
        sx += bf2f((unsigned short)(v & 0xffff));
        sy += bf2f((unsigned short)(v >> 16));
    }
    float inv = 1.0f / fmaxf((float)(end - beg), 1.0f);
    unsigned o = (unsigned)f2bf(sx * inv) | ((unsigned)f2bf(sy * inv) << 16);
    *(unsigned*)&outp[(size_t)node * 128 + lane * 2] = o;
}

// ---------------- MFMA GEMM: out = f(A@W [+ A2@W2] + b [+ out]) ----------------
// block = 256 thr = 4 waves; tile 64 rows x 128 cols; wave = 16 rows x 128 cols.

template<int DUAL, int DOELU, int OUTF32, int DOADD>
__global__ __launch_bounds__(256)
void k_mm(const unsigned short* __restrict__ A, const unsigned short* __restrict__ A2,
          const short* __restrict__ Wp, const short* __restrict__ Wp2,
          const float* __restrict__ bias, void* outv) {
    __shared__ short sW[16384];  // 32 KB: 2048 chunks of 16B, linear (prepacked layout)
    __shared__ short sA[8192];   // 16 KB: 64 rows x 16 chunk-slots; slot c holds chunk c^(r&7)
    const int t = threadIdx.x;
    const int wv = t >> 6, lane = t & 63;
    const int row0 = blockIdx.x * 64;
    const int m = lane & 15, g = lane >> 4;

    floatx4 acc[8];
#pragma unroll
    for (int cb = 0; cb < 8; ++cb) acc[cb] = (floatx4){0.f, 0.f, 0.f, 0.f};

    const int npass = DUAL ? 2 : 1;
    for (int pass = 0; pass < npass; ++pass) {
        const unsigned short* Ac = pass ? A2 : A;
        const short* Wc = pass ? Wp2 : Wp;
        __syncthreads();
        // stage W: 2048 x 16B, linear
#pragma unroll
        for (int i = 0; i < 8; ++i) {
            int cbase = (i * 4 + wv) * 64;
            __builtin_amdgcn_global_load_lds(
                (const __attribute__((address_space(1))) unsigned int*)(Wc + (size_t)(cbase + lane) * 8),
                (__attribute__((address_space(3))) unsigned int*)(sW + cbase * 8),
                16, 0, 0);
        }
        // stage A: 1024 x 16B; LDS slot (r,c) <- global chunk (r, c^(r&7))
#pragma unroll
        for (int i = 0; i < 4; ++i) {
            int cbase = (i * 4 + wv) * 64;
            int id = cbase + lane;
            int r = id >> 4, cs = id & 15;
            int rg = row0 + r; if (rg >= NN) rg = 0;
            int csrc = cs ^ (r & 7);
            __builtin_amdgcn_global_load_lds(
                (const __attribute__((address_space(1))) unsigned int*)(Ac + (size_t)rg * 128 + csrc * 8),
                (__attribute__((address_space(3))) unsigned int*)(sA + cbase * 8),
                16, 0, 0);
        }
        __syncthreads();

        const int r0 = wv * 16;
#pragma unroll
        for (int ks = 0; ks < 4; ++ks) {
            short8 af = *(const short8*)&sA[((r0 + m) * 16 + (((ks * 4 + g) ^ (m & 7)))) * 8];
#pragma unroll
            for (int cb = 0; cb < 8; ++cb) {
                short8 bf = *(const short8*)&sW[((cb * 4 + ks) * 64 + lane) * 8];
                acc[cb] = __builtin_amdgcn_mfma_f32_16x16x32_bf16(af, bf, acc[cb], 0, 0, 0);
            }
        }
    }

    // epilogue: C/D layout col=lane&15, row=(lane>>4)*4+reg
    int rowbase = row0 + wv * 16 + g * 4;
#pragma unroll
    for (int cb = 0; cb < 8; ++cb) {
        int C = cb * 16 + m;
        float bb = bias[C];
#pragma unroll
        for (int rr = 0; rr < 4; ++rr) {
            int R = rowbase + rr;
            if (R < NN) {
                float v = acc[cb][rr] + bb;
                if (DOELU) v = (v > 0.f) ? v : expm1f(v);
                if (OUTF32) {
                    float* o = (float*)outv;
                    size_t idx = (size_t)R * 128 + C;
                    if (DOADD) v += o[idx];
                    o[idx] = v;
                } else {
                    unsigned short* o = (unsigned short*)outv;
                    o[(size_t)R * 128 + C] = f2bf(v);
                }
            }
        }
    }
}

// ---------------- launch ----------------

extern "C" void kernel_launch(void* const* d_in, const int* in_sizes, int n_in,
                              void* d_out, int out_size, void* d_ws, size_t ws_size,
                              hipStream_t stream) {
    const float* h        = (const float*)d_in[0];
    const int*   src      = (const int*)d_in[1];
    const int*   dst      = (const int*)d_in[2];
    const float* W_skip1  = (const float*)d_in[3];
    const float* b_skip1  = (const float*)d_in[4];
    const float* W_skip2  = (const float*)d_in[5];
    const float* b_skip2  = (const float*)d_in[6];
    const float* W_self1  = (const float*)d_in[7];
    const float* W_neigh1 = (const float*)d_in[8];
    const float* b_conv1  = (const float*)d_in[9];
    const float* W_si1    = (const float*)d_in[10];
    const float* b_si1    = (const float*)d_in[11];
    const float* W_si2    = (const float*)d_in[12];
    const float* b_si2    = (const float*)d_in[13];
    const float* W_self2  = (const float*)d_in[14];
    const float* W_neigh2 = (const float*)d_in[15];
    const float* b_conv2  = (const float*)d_in[16];
    float* out = (float*)d_out;

    char* ws = (char*)d_ws;
    int* deg       = (int*)ws;            // [50048]
    int* cursor    = deg + 50048;         // [50048]
    int* row_start = deg + 100096;        // [50001] (padded region to 150208)
    int* partials  = deg + 150208;        // [64]
    int* col_idx   = deg + 150272;        // [800000]  -> ends at int 950272 = byte 3801088
    short* wpk          = (short*)(ws + 3801088);            // 8 x 16384 bf16 = 256 KB
    unsigned short* hB  = (unsigned short*)(ws + 4063232);   // 6.4M bf16
    unsigned short* B1  = (unsigned short*)(ws + 16863232);  // 6.4M bf16
    unsigned short* B2  = (unsigned short*)(ws + 29663232);  // 6.4M bf16

    hipMemsetAsync(ws, 0, 100096 * sizeof(int), stream);

    k_hist<<<(NE + 255) / 256, 256, 0, stream>>>(dst, deg);
    k_scan_part<<<49, 1024, 0, stream>>>(deg, partials);
    k_scan_top<<<1, 64, 0, stream>>>(partials, row_start, 49);
    k_scan_final<<<49, 1024, 0, stream>>>(deg, partials, row_start);
    k_scatter<<<(NE + 255) / 256, 256, 0, stream>>>(src, dst, row_start, cursor, col_idx);

    k_packW<<<8, 256, 0, stream>>>(W_skip1, W_skip2, W_self1, W_neigh1,
                                   W_si1, W_si2, W_self2, W_neigh2, wpk);
    k_cvt<<<3125, 256, 0, stream>>>(h, hB);

    const int GB = (NN + 63) / 64;  // 782

    // h_skip: B1 = ELU(h@Ws1+b); out = B1@Ws2+b
    k_mm<0, 1, 0, 0><<<GB, 256, 0, stream>>>(hB, nullptr, wpk, nullptr, b_skip1, B1);
    k_mm<0, 0, 1, 0><<<GB, 256, 0, stream>>>(B1, nullptr, wpk + 16384, nullptr, b_skip2, out);

    // SAGE 1: B2 = agg(hB); B1 = ELU(hB@Wself1 + B2@Wneigh1 + b)
    k_agg<<<(NN * 64) / 256 + 1, 256, 0, stream>>>(hB, row_start, col_idx, B2);
    k_mm<1, 1, 0, 0><<<GB, 256, 0, stream>>>(hB, B2, wpk + 2 * 16384, wpk + 3 * 16384, b_conv1, B1);

    // self-interaction: B2 = ELU(B1@Wsi1+b); B1 = ELU(B2@Wsi2+b)
    k_mm<0, 1, 0, 0><<<GB, 256, 0, stream>>>(B1, nullptr, wpk + 4 * 16384, nullptr, b_si1, B2);
    k_mm<0, 1, 0, 0><<<GB, 256, 0, stream>>>(B2, nullptr, wpk + 5 * 16384, nullptr, b_si2, B1);

    // SAGE 2 + residual: B2 = agg(B1); out += B1@Wself2 + B2@Wneigh2 + b
    k_agg<<<(NN * 64) / 256 + 1, 256, 0, stream>>>(B1, row_start, col_idx, B2);
    k_mm<1, 0, 1, 1><<<GB, 256, 0, stream>>>(B1, B2, wpk + 6 * 16384, wpk + 7 * 16384, b_conv2, out);
}

// Round 4
// 287.443 us; speedup vs baseline: 1.9404x; 1.3520x over previous
//
#include <hip/hip_runtime.h>
#include <math.h>

#define NN 50000
#define NE 800000

typedef __attribute__((ext_vector_type(8))) short short8;
typedef __attribute__((ext_vector_type(4))) float floatx4;

__device__ __forceinline__ unsigned short f2bf(float f) {
    unsigned u = __float_as_uint(f);
    unsigned r = (u + 0x7fff + ((u >> 16) & 1)) >> 16;
    return (unsigned short)r;
}
__device__ __forceinline__ float bf2f(unsigned short h) {
    return __uint_as_float(((unsigned)h) << 16);
}

// ---------------- CSR build ----------------

__global__ void k_hist(const int* __restrict__ dst, int* __restrict__ deg) {
    int e = blockIdx.x * blockDim.x + threadIdx.x;
    if (e < NE) atomicAdd(&deg[dst[e]], 1);
}

__global__ void k_scan_part(const int* __restrict__ deg, int* __restrict__ partials) {
    __shared__ int s[1024];
    int idx = blockIdx.x * 1024 + threadIdx.x;
    s[threadIdx.x] = (idx < NN) ? deg[idx] : 0;
    for (int off = 512; off > 0; off >>= 1) {
        __syncthreads();
        if (threadIdx.x < off) s[threadIdx.x] += s[threadIdx.x + off];
    }
    if (threadIdx.x == 0) partials[blockIdx.x] = s[0];
}

__global__ void k_scan_top(int* __restrict__ partials, int* __restrict__ row_start, int n) {
    if (threadIdx.x == 0 && blockIdx.x == 0) {
        int acc = 0;
        for (int i = 0; i < n; ++i) { int v = partials[i]; partials[i] = acc; acc += v; }
        row_start[NN] = acc;
    }
}

__global__ void k_scan_final(const int* __restrict__ deg, const int* __restrict__ partials,
                             int* __restrict__ row_start) {
    __shared__ int s[1024];
    int idx = blockIdx.x * 1024 + threadIdx.x;
    int v = (idx < NN) ? deg[idx] : 0;
    s[threadIdx.x] = v;
    for (int off = 1; off < 1024; off <<= 1) {
        __syncthreads();
        int tmp = (threadIdx.x >= off) ? s[threadIdx.x - off] : 0;
        __syncthreads();
        s[threadIdx.x] += tmp;
    }
    if (idx < NN) row_start[idx] = partials[blockIdx.x] + s[threadIdx.x] - v;
}

__global__ void k_scatter(const int* __restrict__ src, const int* __restrict__ dst,
                          const int* __restrict__ row_start, int* __restrict__ cursor,
                          int* __restrict__ col_idx) {
    int e = blockIdx.x * blockDim.x + threadIdx.x;
    if (e < NE) {
        int d = dst[e];
        int slot = atomicAdd(&cursor[d], 1);
        col_idx[row_start[d] + slot] = src[e];
    }
}

// ---------------- f32 -> bf16 convert ----------------

__global__ __launch_bounds__(256)
void k_cvt(const float* __restrict__ src, unsigned short* __restrict__ dst) {
    int i = (blockIdx.x * 256 + threadIdx.x) * 8;
    float4 a = *(const float4*)&src[i];
    float4 b = *(const float4*)&src[i + 4];
    short8 v;
    v[0] = (short)f2bf(a.x); v[1] = (short)f2bf(a.y);
    v[2] = (short)f2bf(a.z); v[3] = (short)f2bf(a.w);
    v[4] = (short)f2bf(b.x); v[5] = (short)f2bf(b.y);
    v[6] = (short)f2bf(b.z); v[7] = (short)f2bf(b.w);
    *(short8*)&dst[i] = v;
}

// ---------------- pack W (f32 [128][128]) into MFMA-B bf16 layout ----------------
// chunk q = (cb*4 + ks)*64 + lane, lane = n + 16*g: holds W[ks*32+g*8+j][cb*16+n], j=0..7

__global__ __launch_bounds__(256)
void k_packW(const float* w0, const float* w1, const float* w2, const float* w3,
             const float* w4, const float* w5, const float* w6, const float* w7,
             short* __restrict__ wpk) {
    const float* W;
    switch (blockIdx.x) {
        case 0: W = w0; break; case 1: W = w1; break;
        case 2: W = w2; break; case 3: W = w3; break;
        case 4: W = w4; break; case 5: W = w5; break;
        case 6: W = w6; break; default: W = w7; break;
    }
    short* dst = wpk + (size_t)blockIdx.x * 16384;
#pragma unroll
    for (int i = 0; i < 8; ++i) {
        int q = threadIdx.x + i * 256;
        int cb = q >> 8, ks = (q >> 6) & 3, lane = q & 63;
        int n = lane & 15, g = lane >> 4;
        int col = cb * 16 + n, krow = ks * 32 + g * 8;
        short8 v;
#pragma unroll
        for (int j = 0; j < 8; ++j)
            v[j] = (short)f2bf(W[(krow + j) * 128 + col]);
        *(short8*)&dst[q * 8] = v;
    }
}

// ---------------- mean aggregation (wave per node, bf16 feats) ----------------
// batched vector loads: 8 idx loads then 8 feature loads in flight

__global__ __launch_bounds__(256)
void k_agg(const unsigned short* __restrict__ feat, const int* __restrict__ row_start,
           const int* __restrict__ col_idx, unsigned short* __restrict__ outp) {
    int node = (blockIdx.x * 256 + threadIdx.x) >> 6;
    int lane = threadIdx.x & 63;
    if (node >= NN) return;
    const int beg = row_start[node], end = row_start[node + 1];
    const size_t lo = (size_t)(lane * 2);
    float sx = 0.f, sy = 0.f;
    int j = beg;
#pragma unroll 1
    for (; j + 8 <= end; j += 8) {
        int s[8];
#pragma unroll
        for (int u = 0; u < 8; ++u) s[u] = col_idx[j + u];
        unsigned v[8];
#pragma unroll
        for (int u = 0; u < 8; ++u)
            v[u] = *(const unsigned*)&feat[(size_t)s[u] * 128 + lo];
#pragma unroll
        for (int u = 0; u < 8; ++u) {
            sx += bf2f((unsigned short)(v[u] & 0xffff));
            sy += bf2f((unsigned short)(v[u] >> 16));
        }
    }
#pragma unroll 1
    for (; j < end; ++j) {
        int s = col_idx[j];
        unsigned v = *(const unsigned*)&feat[(size_t)s * 128 + lo];
        sx += bf2f((unsigned short)(v & 0xffff));
        sy += bf2f((unsigned short)(v >> 16));
    }
    float inv = 1.0f / fmaxf((float)(end - beg), 1.0f);
    unsigned o = (unsigned)f2bf(sx * inv) | ((unsigned)f2bf(sy * inv) << 16);
    *(unsigned*)&outp[(size_t)node * 128 + lo] = o;
}

// ---------------- MFMA GEMM: out = f(A@W [+ A2@W2] + b [+ out]) ----------------
// block = 256 thr = 4 waves; tile 128 rows x 128 cols; wave = 32 rows (2 frags) x 128 cols.

template<int DUAL, int DOELU, int OUTF32, int DOADD>
__global__ __launch_bounds__(256)
void k_mm(const unsigned short* __restrict__ A, const unsigned short* __restrict__ A2,
          const short* __restrict__ Wp, const short* __restrict__ Wp2,
          const float* __restrict__ bias, void* outv) {
    __shared__ short sW[16384];  // 32 KB: 2048 chunks of 16B, linear (prepacked layout)
    __shared__ short sA[16384];  // 32 KB: 128 rows x 16 chunk-slots; slot c holds chunk c^(r&7)
    const int t = threadIdx.x;
    const int wv = t >> 6, lane = t & 63;
    const int row0 = blockIdx.x * 128;
    const int m = lane & 15, g = lane >> 4;

    floatx4 acc0[8], acc1[8];
#pragma unroll
    for (int cb = 0; cb < 8; ++cb) {
        acc0[cb] = (floatx4){0.f, 0.f, 0.f, 0.f};
        acc1[cb] = (floatx4){0.f, 0.f, 0.f, 0.f};
    }

    const int npass = DUAL ? 2 : 1;
    for (int pass = 0; pass < npass; ++pass) {
        const unsigned short* Ac = pass ? A2 : A;
        const short* Wc = pass ? Wp2 : Wp;
        __syncthreads();
        // stage W: 2048 x 16B, linear
#pragma unroll
        for (int i = 0; i < 8; ++i) {
            int cbase = (i * 4 + wv) * 64;
            __builtin_amdgcn_global_load_lds(
                (const __attribute__((address_space(1))) unsigned int*)(Wc + (size_t)(cbase + lane) * 8),
                (__attribute__((address_space(3))) unsigned int*)(sW + cbase * 8),
                16, 0, 0);
        }
        // stage A: 2048 x 16B; LDS slot (r,c) <- global chunk (r, c^(r&7))
#pragma unroll
        for (int i = 0; i < 8; ++i) {
            int cbase = (i * 4 + wv) * 64;
            int id = cbase + lane;
            int r = id >> 4, cs = id & 15;
            int rg = row0 + r; if (rg >= NN) rg = NN - 1;
            int csrc = cs ^ (r & 7);
            __builtin_amdgcn_global_load_lds(
                (const __attribute__((address_space(1))) unsigned int*)(Ac + (size_t)rg * 128 + csrc * 8),
                (__attribute__((address_space(3))) unsigned int*)(sA + cbase * 8),
                16, 0, 0);
        }
        // explicit drain hedge: make LDS-visibility of global_load_lds unconditional
        asm volatile("s_waitcnt vmcnt(0)" ::: "memory");
        __builtin_amdgcn_sched_barrier(0);
        __syncthreads();

        const int r0 = wv * 32;
#pragma unroll
        for (int ks = 0; ks < 4; ++ks) {
            int cxor = (ks * 4 + g) ^ (m & 7);
            short8 af0 = *(const short8*)&sA[((r0 + m) * 16 + cxor) * 8];
            short8 af1 = *(const short8*)&sA[((r0 + 16 + m) * 16 + cxor) * 8];
#pragma unroll
            for (int cb = 0; cb < 8; ++cb) {
                short8 bf = *(const short8*)&sW[((cb * 4 + ks) * 64 + lane) * 8];
                acc0[cb] = __builtin_amdgcn_mfma_f32_16x16x32_bf16(af0, bf, acc0[cb], 0, 0, 0);
                acc1[cb] = __builtin_amdgcn_mfma_f32_16x16x32_bf16(af1, bf, acc1[cb], 0, 0, 0);
            }
        }
    }

    // epilogue: C/D layout col=lane&15, row=(lane>>4)*4+reg
    const int rowbase = row0 + wv * 32 + g * 4;
#pragma unroll
    for (int f = 0; f < 2; ++f) {
#pragma unroll
        for (int cb = 0; cb < 8; ++cb) {
            int C = cb * 16 + m;
            float bb = bias[C];
            const floatx4* ac = f ? &acc1[cb] : &acc0[cb];
#pragma unroll
            for (int rr = 0; rr < 4; ++rr) {
                int R = rowbase + f * 16 + rr;
                if (R < NN) {
                    float v = (*ac)[rr] + bb;
                    if (DOELU) v = (v > 0.f) ? v : expm1f(v);
                    if (OUTF32) {
                        float* o = (float*)outv;
                        size_t idx = (size_t)R * 128 + C;
                        if (DOADD) v += o[idx];
                        o[idx] = v;
                    } else {
                        unsigned short* o = (unsigned short*)outv;
                        o[(size_t)R * 128 + C] = f2bf(v);
                    }
                }
            }
        }
    }
}

// ---------------- launch ----------------

extern "C" void kernel_launch(void* const* d_in, const int* in_sizes, int n_in,
                              void* d_out, int out_size, void* d_ws, size_t ws_size,
                              hipStream_t stream) {
    const float* h        = (const float*)d_in[0];
    const int*   src      = (const int*)d_in[1];
    const int*   dst      = (const int*)d_in[2];
    const float* W_skip1  = (const float*)d_in[3];
    const float* b_skip1  = (const float*)d_in[4];
    const float* W_skip2  = (const float*)d_in[5];
    const float* b_skip2  = (const float*)d_in[6];
    const float* W_self1  = (const float*)d_in[7];
    const float* W_neigh1 = (const float*)d_in[8];
    const float* b_conv1  = (const float*)d_in[9];
    const float* W_si1    = (const float*)d_in[10];
    const float* b_si1    = (const float*)d_in[11];
    const float* W_si2    = (const float*)d_in[12];
    const float* b_si2    = (const float*)d_in[13];
    const float* W_self2  = (const float*)d_in[14];
    const float* W_neigh2 = (const float*)d_in[15];
    const float* b_conv2  = (const float*)d_in[16];
    float* out = (float*)d_out;

    char* ws = (char*)d_ws;
    int* deg       = (int*)ws;            // [50048]
    int* cursor    = deg + 50048;         // [50048]
    int* row_start = deg + 100096;        // [50001] (padded region to 150208)
    int* partials  = deg + 150208;        // [64]
    int* col_idx   = deg + 150272;        // [800000]  -> ends at byte 3801088
    short* wpk          = (short*)(ws + 3801088);            // 8 x 16384 bf16 = 256 KB
    unsigned short* hB  = (unsigned short*)(ws + 4063232);   // 6.4M bf16
    unsigned short* B1  = (unsigned short*)(ws + 16863232);  // 6.4M bf16
    unsigned short* B2  = (unsigned short*)(ws + 29663232);  // 6.4M bf16

    hipMemsetAsync(ws, 0, 100096 * sizeof(int), stream);

    k_hist<<<(NE + 255) / 256, 256, 0, stream>>>(dst, deg);
    k_scan_part<<<49, 1024, 0, stream>>>(deg, partials);
    k_scan_top<<<1, 64, 0, stream>>>(partials, row_start, 49);
    k_scan_final<<<49, 1024, 0, stream>>>(deg, partials, row_start);
    k_scatter<<<(NE + 255) / 256, 256, 0, stream>>>(src, dst, row_start, cursor, col_idx);

    k_packW<<<8, 256, 0, stream>>>(W_skip1, W_skip2, W_self1, W_neigh1,
                                   W_si1, W_si2, W_self2, W_neigh2, wpk);
    k_cvt<<<3125, 256, 0, stream>>>(h, hB);

    const int GB = (NN + 127) / 128;  // 391

    // h_skip: B1 = ELU(h@Ws1+b); out = B1@Ws2+b
    k_mm<0, 1, 0, 0><<<GB, 256, 0, stream>>>(hB, nullptr, wpk, nullptr, b_skip1, B1);
    k_mm<0, 0, 1, 0><<<GB, 256, 0, stream>>>(B1, nullptr, wpk + 16384, nullptr, b_skip2, out);

    // SAGE 1: B2 = agg(hB); B1 = ELU(hB@Wself1 + B2@Wneigh1 + b)
    k_agg<<<(NN * 64) / 256 + 1, 256, 0, stream>>>(hB, row_start, col_idx, B2);
    k_mm<1, 1, 0, 0><<<GB, 256, 0, stream>>>(hB, B2, wpk + 2 * 16384, wpk + 3 * 16384, b_conv1, B1);

    // self-interaction: B2 = ELU(B1@Wsi1+b); B1 = ELU(B2@Wsi2+b)
    k_mm<0, 1, 0, 0><<<GB, 256, 0, stream>>>(B1, nullptr, wpk + 4 * 16384, nullptr, b_si1, B2);
    k_mm<0, 1, 0, 0><<<GB, 256, 0, stream>>>(B2, nullptr, wpk + 5 * 16384, nullptr, b_si2, B1);

    // SAGE 2 + residual: B2 = agg(B1); out += B1@Wself2 + B2@Wneigh2 + b
    k_agg<<<(NN * 64) / 256 + 1, 256, 0, stream>>>(B1, row_start, col_idx, B2);
    k_mm<1, 0, 1, 1><<<GB, 256, 0, stream>>>(B1, B2, wpk + 6 * 16384, wpk + 7 * 16384, b_conv2, out);
}